// Round 1
// baseline (1862.593 us; speedup 1.0000x reference)
//
#include <hip/hip_runtime.h>
#include <stdint.h>

// Problem constants (fixed by the reference)
#define M_TOT 16384   // B*S
#define K_TOT 4864    // IN_DIM
#define N_TOT 640     // G*V
#define GRP   2
#define NV    320
#define CVD   128     // CV_DIM / G

// GEMM tile
#define BM 128
#define BN 128
#define BK 16
#define PAD_A (BM + 4)   // pad so transposed staging writes spread banks

__device__ __forceinline__ unsigned int mono_u32(float f) {
    unsigned int b = __float_as_uint(f);
    // monotone map fp32 -> u32 (order-preserving, incl. negatives)
    return b ^ ((unsigned int)((int)b >> 31) | 0x80000000u);
}

__global__ __launch_bounds__(256, 2)
void gemm_argmax(const float* __restrict__ A, const float* __restrict__ Wm,
                 const float* __restrict__ bias,
                 unsigned long long* __restrict__ packed)
{
    __shared__ float sA[BK][PAD_A];
    __shared__ float sB[BK][BN];
    __shared__ float          sVal[2][BM][17];
    __shared__ unsigned short sCol[2][BM][17];

    const int tid = threadIdx.x;
    const int tx = tid & 15;
    const int ty = tid >> 4;
    const int bxc = blockIdx.x;   // col tile 0..4 (fastest -> L2/L3 A-tile sharing)
    const int by  = blockIdx.y;   // row tile 0..127
    const int m0 = by * BM;
    const int n0 = bxc * BN;

    // staging index math
    const int arow = tid >> 2;         // 0..63
    const int akc  = (tid & 3) << 2;   // 0,4,8,12
    const int brow = tid >> 5;         // 0..7
    const int bcol = (tid & 31) << 2;  // 0..124

    const float* Aptr0 = A + (size_t)(m0 + arow) * K_TOT + akc;
    const float* Aptr1 = Aptr0 + (size_t)64 * K_TOT;
    const float* Bptr0 = Wm + (size_t)brow * N_TOT + n0 + bcol;
    const float* Bptr1 = Bptr0 + (size_t)8 * N_TOT;

    float acc[8][8];
#pragma unroll
    for (int i = 0; i < 8; ++i)
#pragma unroll
        for (int j = 0; j < 8; ++j) acc[i][j] = 0.f;

    for (int k0 = 0; k0 < K_TOT; k0 += BK) {
        float4 a0 = *(const float4*)(Aptr0 + k0);
        float4 a1 = *(const float4*)(Aptr1 + k0);
        float4 b0 = *(const float4*)(Bptr0 + (size_t)k0 * N_TOT);
        float4 b1 = *(const float4*)(Bptr1 + (size_t)k0 * N_TOT);
        __syncthreads();   // previous iteration's LDS reads complete
        sA[akc + 0][arow] = a0.x;
        sA[akc + 1][arow] = a0.y;
        sA[akc + 2][arow] = a0.z;
        sA[akc + 3][arow] = a0.w;
        sA[akc + 0][64 + arow] = a1.x;
        sA[akc + 1][64 + arow] = a1.y;
        sA[akc + 2][64 + arow] = a1.z;
        sA[akc + 3][64 + arow] = a1.w;
        *(float4*)&sB[brow][bcol]     = b0;
        *(float4*)&sB[brow + 8][bcol] = b1;
        __syncthreads();
#pragma unroll
        for (int kk = 0; kk < BK; ++kk) {
            float4 va0 = *(const float4*)&sA[kk][ty * 4];
            float4 va1 = *(const float4*)&sA[kk][64 + ty * 4];
            float4 vb0 = *(const float4*)&sB[kk][tx * 4];
            float4 vb1 = *(const float4*)&sB[kk][64 + tx * 4];
            float av[8] = {va0.x, va0.y, va0.z, va0.w, va1.x, va1.y, va1.z, va1.w};
            float bv[8] = {vb0.x, vb0.y, vb0.z, vb0.w, vb1.x, vb1.y, vb1.z, vb1.w};
#pragma unroll
            for (int i = 0; i < 8; ++i)
#pragma unroll
                for (int j = 0; j < 8; ++j)
                    acc[i][j] = fmaf(av[i], bv[j], acc[i][j]);
        }
    }

    // ---- per-thread argmax candidates (each 64-col half is one group: 320 % 64 == 0)
#pragma unroll
    for (int h = 0; h < 2; ++h) {
#pragma unroll
        for (int i = 0; i < 8; ++i) {
            const int r = (i < 4) ? (ty * 4 + i) : (64 + ty * 4 + (i - 4));
            float best = 0.f;
            int bc = 0;
#pragma unroll
            for (int j = 0; j < 4; ++j) {
                float v = acc[i][h * 4 + j] + bias[n0 + h * 64 + tx * 4 + j];
                if (j == 0 || v > best) { best = v; bc = j; }   // strict >: first max wins
            }
            sVal[h][r][tx] = best;
            sCol[h][r][tx] = (unsigned short)(tx * 4 + bc);
        }
    }
    __syncthreads();

    // ---- reduce 16 candidates per (row, half); tx ascending == col ascending (tie-break)
    {
        const int h = tid >> 7;
        const int r = tid & 127;
        float best = sVal[h][r][0];
        int bc = sCol[h][r][0];
#pragma unroll
        for (int t2 = 1; t2 < 16; ++t2) {
            float v = sVal[h][r][t2];
            if (v > best) { best = v; bc = sCol[h][r][t2]; }
        }
        const int gch = n0 + h * 64;        // global col of this half's base
        const int grp = gch / NV;           // 0 or 1
        const int lc  = gch - grp * NV + bc; // col within group [0,320)
        unsigned long long pv =
            ((unsigned long long)mono_u32(best) << 32) |
            (unsigned int)(NV - 1 - lc);     // bigger = smaller col on logit ties
        atomicMax(&packed[(size_t)(m0 + r) * GRP + grp], pv);
    }
}

__global__ __launch_bounds__(256)
void gather_hist(const unsigned long long* __restrict__ packed,
                 const float* __restrict__ cv,
                 float* __restrict__ out, int* __restrict__ counts)
{
    const int m = blockIdx.x;
    const int t = threadIdx.x;        // 256
    const int g = t >> 7;             // 0/1
    const unsigned long long p = packed[(size_t)m * GRP + g];
    const int idx = (NV - 1) - (int)(p & 0xFFFFFFFFull);
    const int c = t & 127;
    out[(size_t)m * (GRP * CVD) + t] = cv[((size_t)g * NV + idx) * CVD + c];
    if (c == 0) atomicAdd(&counts[g * NV + idx], 1);
}

__global__ void perplexity_k(const int* __restrict__ counts, float* __restrict__ outp)
{
    __shared__ float sred[GRP * NV];
    const int t = threadIdx.x;        // 640
    const float marg = (float)counts[t] * (1.0f / (float)M_TOT);
    sred[t] = marg * logf(marg + 1e-7f);
    __syncthreads();
    if (t < GRP) {
        float s = 0.f;
        for (int i = 0; i < NV; ++i) s += sred[t * NV + i];
        sred[t] = expf(-s);
    }
    __syncthreads();
    if (t == 0) outp[0] = sred[0] + sred[1];
}

extern "C" void kernel_launch(void* const* d_in, const int* in_sizes, int n_in,
                              void* d_out, int out_size, void* d_ws, size_t ws_size,
                              hipStream_t stream)
{
    const float* A    = (const float*)d_in[0];   // (16,1024,4864) f32
    const float* Wm   = (const float*)d_in[1];   // (4864,640) f32
    const float* bias = (const float*)d_in[2];   // (640,) f32
    const float* cv   = (const float*)d_in[3];   // (1,640,128) f32
    // d_in[4] = num_groups (==2), baked into constants

    float* out = (float*)d_out;                       // (16,1024,256)
    float* ppl = out + (size_t)M_TOT * (GRP * CVD);   // +1 scalar

    unsigned long long* packed = (unsigned long long*)d_ws;            // M x G
    int* counts = (int*)((char*)d_ws + (size_t)M_TOT * GRP * 8);       // G*NV

    const size_t zbytes = (size_t)M_TOT * GRP * 8 + (size_t)GRP * NV * 4;
    hipMemsetAsync(d_ws, 0, zbytes, stream);

    dim3 grid(N_TOT / BN, M_TOT / BM);   // x = col tile fastest (A-tile L2/L3 sharing)
    gemm_argmax<<<grid, 256, 0, stream>>>(A, Wm, bias, packed);
    gather_hist<<<M_TOT, 256, 0, stream>>>(packed, cv, out, counts);
    perplexity_k<<<1, GRP * NV, 0, stream>>>(counts, ppl);
}

// Round 2
// 1596.642 us; speedup vs baseline: 1.1666x; 1.1666x over previous
//
#include <hip/hip_runtime.h>
#include <stdint.h>

// Problem constants (fixed by the reference)
#define M_TOT 16384   // B*S
#define K_TOT 4864    // IN_DIM
#define N_TOT 640     // G*V
#define GRP   2
#define NV    320
#define CVD   128     // CV_DIM / G

// GEMM tile
#define BM 64
#define BN 128
#define BK 16
#define PAD_A 68      // 68*4B: akc*68 -> bank offset {0,16,0,16}: 2-way (free); keeps 16B align

typedef float f32x2 __attribute__((ext_vector_type(2)));

__device__ __forceinline__ unsigned int mono_u32(float f) {
    unsigned int b = __float_as_uint(f);
    // monotone map fp32 -> u32 (order-preserving, incl. negatives)
    return b ^ ((unsigned int)((int)b >> 31) | 0x80000000u);
}

__global__ __launch_bounds__(256, 4)
void gemm_argmax(const float* __restrict__ A, const float* __restrict__ Wm,
                 const float* __restrict__ bias,
                 unsigned long long* __restrict__ packed)
{
    __shared__ float sA[BK][PAD_A];   // transposed A tile: sA[k][m]
    __shared__ float sB[BK][BN];

    const int tid = threadIdx.x;
    const int tx = tid & 15;          // col group: cols tx*4..+3 and 64+tx*4..+3
    const int ty = tid >> 4;          // 0..15: rows ty*4..+3
    const int n0 = blockIdx.x * BN;   // col tile fastest -> A-tile L2 sharing
    const int m0 = blockIdx.y * BM;

    // staging index math (1x float4 of A, 2x float4 of B per thread)
    const int arow = tid >> 2;         // 0..63
    const int akc  = (tid & 3) << 2;   // 0,4,8,12
    const int brow = tid >> 5;         // 0..7
    const int bcol = (tid & 31) << 2;  // 0..124

    const float* Ap  = A  + (size_t)(m0 + arow) * K_TOT + akc;
    const float* Bp0 = Wm + (size_t)brow * N_TOT + n0 + bcol;
    const float* Bp1 = Bp0 + (size_t)8 * N_TOT;

    const float4 bias0 = *(const float4*)(bias + n0 + tx * 4);
    const float4 bias1 = *(const float4*)(bias + n0 + 64 + tx * 4);

    f32x2 acc[4][4];                  // [row i][col pair: h*2 + (0|1)]
#pragma unroll
    for (int i = 0; i < 4; ++i)
#pragma unroll
        for (int j = 0; j < 4; ++j) acc[i][j] = (f32x2){0.f, 0.f};

    // software pipeline: regs hold tile k0; next tile loads issue before compute
    float4 ra  = *(const float4*)(Ap);
    float4 rb0 = *(const float4*)(Bp0);
    float4 rb1 = *(const float4*)(Bp1);

    for (int k0 = 0;;) {
        __syncthreads();   // previous iteration's LDS reads complete
        sA[akc + 0][arow] = ra.x;
        sA[akc + 1][arow] = ra.y;
        sA[akc + 2][arow] = ra.z;
        sA[akc + 3][arow] = ra.w;
        *(float4*)&sB[brow][bcol]     = rb0;
        *(float4*)&sB[brow + 8][bcol] = rb1;
        __syncthreads();
        k0 += BK;
        if (k0 < K_TOT) {              // prefetch next tile; waitcnt lands next iter
            ra  = *(const float4*)(Ap + k0);
            rb0 = *(const float4*)(Bp0 + (size_t)k0 * N_TOT);
            rb1 = *(const float4*)(Bp1 + (size_t)k0 * N_TOT);
        }
#pragma unroll
        for (int kk = 0; kk < BK; ++kk) {
            float4 va  = *(const float4*)&sA[kk][ty * 4];       // 4-addr broadcast, free
            float4 vb0 = *(const float4*)&sB[kk][tx * 4];       // contiguous, conflict-free
            float4 vb1 = *(const float4*)&sB[kk][64 + tx * 4];
            f32x2 b0 = {vb0.x, vb0.y}, b1 = {vb0.z, vb0.w};
            f32x2 b2 = {vb1.x, vb1.y}, b3 = {vb1.z, vb1.w};
            float av[4] = {va.x, va.y, va.z, va.w};
#pragma unroll
            for (int i = 0; i < 4; ++i) {
                f32x2 ai = {av[i], av[i]};
                acc[i][0] = __builtin_elementwise_fma(ai, b0, acc[i][0]);
                acc[i][1] = __builtin_elementwise_fma(ai, b1, acc[i][1]);
                acc[i][2] = __builtin_elementwise_fma(ai, b2, acc[i][2]);
                acc[i][3] = __builtin_elementwise_fma(ai, b3, acc[i][3]);
            }
        }
        if (k0 >= K_TOT) break;
    }

    // ---- argmax epilogue, all in-register via shuffles.
    // Each 64-col half lies in one group (320 % 64 == 0). 16 lanes (tx=0..15,
    // same ty) hold one row's 64 cols; xor-shuffle widths 1,2,4,8 reduce them.
#pragma unroll
    for (int h = 0; h < 2; ++h) {
        const int gch = n0 + h * 64;          // global col of this half's base
        const int grp = gch / NV;             // 0 or 1
        const int cbase = gch - grp * NV + tx * 4;  // col-in-group of j=0
        const float4 bb = h ? bias1 : bias0;
#pragma unroll
        for (int i = 0; i < 4; ++i) {
            float v[4] = {acc[i][h * 2 + 0].x + bb.x, acc[i][h * 2 + 0].y + bb.y,
                          acc[i][h * 2 + 1].x + bb.z, acc[i][h * 2 + 1].y + bb.w};
            float best = v[0]; int bc = 0;
#pragma unroll
            for (int j = 1; j < 4; ++j)
                if (v[j] > best) { best = v[j]; bc = j; }   // strict >: first max wins
            unsigned long long pv =
                ((unsigned long long)mono_u32(best) << 32) |
                (unsigned int)(NV - 1 - (cbase + bc));       // bigger = smaller col on ties
#pragma unroll
            for (int msk = 1; msk < 16; msk <<= 1) {
                unsigned long long o = __shfl_xor(pv, msk);
                if (o > pv) pv = o;
            }
            if (tx == 0)
                atomicMax(&packed[(size_t)(m0 + ty * 4 + i) * GRP + grp], pv);
        }
    }
}

__global__ __launch_bounds__(256)
void gather_hist(const unsigned long long* __restrict__ packed,
                 const float* __restrict__ cv,
                 float* __restrict__ out, int* __restrict__ counts)
{
    const int m = blockIdx.x;
    const int t = threadIdx.x;        // 256
    const int g = t >> 7;             // 0/1
    const unsigned long long p = packed[(size_t)m * GRP + g];
    const int idx = (NV - 1) - (int)(p & 0xFFFFFFFFull);
    const int c = t & 127;
    out[(size_t)m * (GRP * CVD) + t] = cv[((size_t)g * NV + idx) * CVD + c];
    if (c == 0) atomicAdd(&counts[g * NV + idx], 1);
}

__global__ void perplexity_k(const int* __restrict__ counts, float* __restrict__ outp)
{
    __shared__ float sred[GRP * NV];
    const int t = threadIdx.x;        // 640
    const float marg = (float)counts[t] * (1.0f / (float)M_TOT);
    sred[t] = marg * logf(marg + 1e-7f);
    __syncthreads();
    if (t < GRP) {
        float s = 0.f;
        for (int i = 0; i < NV; ++i) s += sred[t * NV + i];
        sred[t] = expf(-s);
    }
    __syncthreads();
    if (t == 0) outp[0] = sred[0] + sred[1];
}

extern "C" void kernel_launch(void* const* d_in, const int* in_sizes, int n_in,
                              void* d_out, int out_size, void* d_ws, size_t ws_size,
                              hipStream_t stream)
{
    const float* A    = (const float*)d_in[0];   // (16,1024,4864) f32
    const float* Wm   = (const float*)d_in[1];   // (4864,640) f32
    const float* bias = (const float*)d_in[2];   // (640,) f32
    const float* cv   = (const float*)d_in[3];   // (1,640,128) f32
    // d_in[4] = num_groups (==2), baked into constants

    float* out = (float*)d_out;                       // (16,1024,256)
    float* ppl = out + (size_t)M_TOT * (GRP * CVD);   // +1 scalar

    unsigned long long* packed = (unsigned long long*)d_ws;            // M x G
    int* counts = (int*)((char*)d_ws + (size_t)M_TOT * GRP * 8);       // G*NV

    const size_t zbytes = (size_t)M_TOT * GRP * 8 + (size_t)GRP * NV * 4;
    hipMemsetAsync(d_ws, 0, zbytes, stream);

    dim3 grid(N_TOT / BN, M_TOT / BM);   // 5 x 256 = 1280 blocks = 5/CU exactly
    gemm_argmax<<<grid, 256, 0, stream>>>(A, Wm, bias, packed);
    gather_hist<<<M_TOT, 256, 0, stream>>>(packed, cv, out, counts);
    perplexity_k<<<1, GRP * NV, 0, stream>>>(counts, ppl);
}

// Round 3
// 807.921 us; speedup vs baseline: 2.3054x; 1.9762x over previous
//
#include <hip/hip_runtime.h>
#include <stdint.h>

// Problem constants (fixed by the reference)
#define M_TOT 16384   // B*S
#define K_TOT 4864    // IN_DIM
#define N_TOT 640     // G*V
#define GRP   2
#define NV    320
#define CVD   128     // CV_DIM / G

// MFMA GEMM tile
#define BM 128
#define BN 320        // one full group per block (bx = group)
#define BK 32
#define KITERS (K_TOT / BK)   // 152

#define MARGIN 2.0e-3f   // 2*eps; approx-logit |err| measured-model ~3e-5 max

typedef __attribute__((ext_vector_type(8))) short short8;
typedef __attribute__((ext_vector_type(4))) float f32x4;

// ---- ws layout (bytes) ----
#define WS_FLAGCNT  0
#define WS_COUNTS   256                      // 640 u32
#define WS_FLAGLIST 4096                     // 65536 u32 (cap > worst case 32768)
#define WS_PACKED   (4096 + 262144)          // 16384*2 u64
#define WS_WT       (1u << 20)               // W_hi_t then W_lo_t, each 640*4864 u16

__device__ __forceinline__ unsigned int mono_u32(float f) {
    unsigned int b = __float_as_uint(f);
    return b ^ ((unsigned int)((int)b >> 31) | 0x80000000u);  // order-preserving
}
__device__ __forceinline__ unsigned short f2bf(float x) {   // RNE, finite inputs
    unsigned int u = __float_as_uint(x);
    return (unsigned short)((u + 0x7fffu + ((u >> 16) & 1u)) >> 16);
}
__device__ __forceinline__ float bf2f(unsigned short h) {
    return __uint_as_float(((unsigned int)h) << 16);
}
__device__ __forceinline__ void gld16(const void* g, void* l) {
    __builtin_amdgcn_global_load_lds(
        (const __attribute__((address_space(1))) unsigned int*)g,
        (__attribute__((address_space(3))) unsigned int*)l, 16, 0, 0);
}

// ---------------- W -> W_hi_t / W_lo_t (bf16, transposed to [n][k]) -------------
__global__ __launch_bounds__(256)
void convert_wt(const float* __restrict__ W, unsigned short* __restrict__ wt)
{
    __shared__ float sW[64][68];
    const int k0 = blockIdx.x * 64;          // 76 tiles
    const int n0 = blockIdx.y * 64;          // 10 tiles
    const int tid = threadIdx.x;
    for (int l = tid; l < 64 * 16; l += 256) {
        int kr = l >> 4, nc = (l & 15) * 4;
        float4 v = *(const float4*)(W + (size_t)(k0 + kr) * N_TOT + n0 + nc);
        sW[kr][nc] = v.x; sW[kr][nc + 1] = v.y; sW[kr][nc + 2] = v.z; sW[kr][nc + 3] = v.w;
    }
    __syncthreads();
    unsigned short* whi = wt;
    unsigned short* wlo = wt + (size_t)N_TOT * K_TOT;
    for (int l = tid; l < 64 * 8; l += 256) {
        int nr = l >> 3, ko = (l & 7) * 8;
        union { short8 v; unsigned short u[8]; } hu, lu;
#pragma unroll
        for (int j = 0; j < 8; ++j) {
            float x = sW[ko + j][nr];
            unsigned short hb = f2bf(x);
            hu.u[j] = hb;
            lu.u[j] = f2bf(x - bf2f(hb));
        }
        size_t off = (size_t)(n0 + nr) * K_TOT + k0 + ko;   // 16B aligned
        *(short8*)(whi + off) = hu.v;
        *(short8*)(wlo + off) = lu.v;
    }
}

// ---------------- MFMA GEMM + argmax(+margin flag) ------------------------------
__device__ __forceinline__ void stage_b(const unsigned short* __restrict__ wt,
                                        short* sBbuf, int bx, int kk, int tid)
{
#pragma unroll
    for (int r = 0; r < 5; ++r) {
        int c = r * 512 + tid;                  // 2560 chunks = hi(1280) + lo(1280)
        int half = (c >= 1280) ? 1 : 0;
        int cc = c - half * 1280;
        int row = cc >> 2, oct = cc & 3;
        const unsigned short* gp = wt + (size_t)half * N_TOT * K_TOT
            + (size_t)(bx * NV + row) * K_TOT + kk + ((oct ^ (row & 3)) << 3);
        gld16(gp, sBbuf + (size_t)c * 8);       // lane-linear dest = [half][row][oct]
    }
}

__global__ __launch_bounds__(512, 2)
void gemm_mfma(const float* __restrict__ A, const unsigned short* __restrict__ wt,
               const float* __restrict__ bias,
               unsigned long long* __restrict__ packed,
               unsigned int* __restrict__ flagcnt, unsigned int* __restrict__ flaglist)
{
    __shared__ short sA[2][2][BM][BK];      // [buf][hi/lo][m][k] 32 KB
    __shared__ short sB[2][2][BN][BK];      // [buf][hi/lo][n][k] 80 KB
    __shared__ uint4 sRed[BM][4];           // cross-wave argmax merge, 8 KB

    const int tid  = threadIdx.x;
    const int L    = tid & 63;
    const int w    = tid >> 6;        // 0..7
    const int quad = L >> 4;
    const int lrow = L & 15;
    const int wrow = w >> 2;          // 0..1 : rows wrow*64..
    const int wcol = w & 3;           // 0..3 : cols wcol*80..
    const int bx   = blockIdx.x;      // group 0/1
    const int m0   = blockIdx.y * BM;
    const int octr = quad ^ (L & 3);  // XOR-swizzled k-oct for frag reads

    // A staging mapping: thread -> (arow 0..127, aoct 0..3), 8 f32 each
    const int arow = tid >> 2;
    const int aoct = tid & 3;
    const float* Ap = A + (size_t)(m0 + arow) * K_TOT + aoct * 8;
    const int aswz = ((aoct ^ (arow & 3)) << 3);   // element offset in sA row

    f32x4 acc[4][5];
#pragma unroll
    for (int i = 0; i < 4; ++i)
#pragma unroll
        for (int j = 0; j < 5; ++j) acc[i][j] = (f32x4){0.f, 0.f, 0.f, 0.f};

    // ---- prologue: stage tile 0 into buf 0
    {
        stage_b(wt, &sB[0][0][0][0], bx, 0, tid);
        float4 a0 = *(const float4*)(Ap);
        float4 a1 = *(const float4*)(Ap + 4);
        union { short8 v; unsigned short u[8]; } hu, lu;
        float xs[8] = {a0.x, a0.y, a0.z, a0.w, a1.x, a1.y, a1.z, a1.w};
#pragma unroll
        for (int j = 0; j < 8; ++j) {
            unsigned short hb = f2bf(xs[j]);
            hu.u[j] = hb; lu.u[j] = f2bf(xs[j] - bf2f(hb));
        }
        *(short8*)&sA[0][0][arow][aswz] = hu.v;
        *(short8*)&sA[0][1][arow][aswz] = lu.v;
    }
    __syncthreads();

    int k0 = 0;
    for (int it = 0; it < KITERS; ++it) {
        const int buf = it & 1;
        const int kn  = k0 + BK;
        float4 a0, a1;
        const bool more = (it + 1 < KITERS);
        if (more) {
            stage_b(wt, &sB[buf ^ 1][0][0][0], bx, kn, tid);  // async into other buf
            a0 = *(const float4*)(Ap + kn);                   // A prefetch (regs)
            a1 = *(const float4*)(Ap + kn + 4);
        }
        // ---- MFMA on buf
        short8 ah[4], al[4];
#pragma unroll
        for (int fi = 0; fi < 4; ++fi) {
            int mloc = wrow * 64 + fi * 16 + lrow;
            ah[fi] = *(const short8*)&sA[buf][0][mloc][octr * 8];
            al[fi] = *(const short8*)&sA[buf][1][mloc][octr * 8];
        }
#pragma unroll
        for (int fj = 0; fj < 5; ++fj) {
            int nloc = wcol * 80 + fj * 16 + lrow;
            short8 bh = *(const short8*)&sB[buf][0][nloc][octr * 8];
            short8 bl = *(const short8*)&sB[buf][1][nloc][octr * 8];
#pragma unroll
            for (int fi = 0; fi < 4; ++fi) {
                acc[fi][fj] = __builtin_amdgcn_mfma_f32_16x16x32_bf16(ah[fi], bh, acc[fi][fj], 0, 0, 0);
                acc[fi][fj] = __builtin_amdgcn_mfma_f32_16x16x32_bf16(ah[fi], bl, acc[fi][fj], 0, 0, 0);
                acc[fi][fj] = __builtin_amdgcn_mfma_f32_16x16x32_bf16(al[fi], bh, acc[fi][fj], 0, 0, 0);
            }
        }
        if (more) {
            union { short8 v; unsigned short u[8]; } hu, lu;
            float xs[8] = {a0.x, a0.y, a0.z, a0.w, a1.x, a1.y, a1.z, a1.w};
#pragma unroll
            for (int j = 0; j < 8; ++j) {
                unsigned short hb = f2bf(xs[j]);
                hu.u[j] = hb; lu.u[j] = f2bf(xs[j] - bf2f(hb));
            }
            *(short8*)&sA[buf ^ 1][0][arow][aswz] = hu.v;
            *(short8*)&sA[buf ^ 1][1][arow][aswz] = lu.v;
        }
        __syncthreads();   // waits gld (issued ~2000cyc ago) + ds_writes
        k0 = kn;
    }

    // ---- epilogue: per-(row) top1(packed) + top2 value over this wave's 80 cols
    float bs[5];
#pragma unroll
    for (int fj = 0; fj < 5; ++fj)
        bs[fj] = bias[bx * NV + wcol * 80 + fj * 16 + lrow];

#pragma unroll
    for (int fi = 0; fi < 4; ++fi) {
#pragma unroll
        for (int r = 0; r < 4; ++r) {
            unsigned long long pv = 0; float v1 = 0.f, v2 = -3.4e38f;
#pragma unroll
            for (int fj = 0; fj < 5; ++fj) {
                float v = acc[fi][fj][r] + bs[fj];
                int cig = wcol * 80 + fj * 16 + lrow;         // col in group
                unsigned long long p = ((unsigned long long)mono_u32(v) << 32)
                                     | (unsigned int)(NV - 1 - cig);
                if (fj == 0) { pv = p; v1 = v; }
                else if (p > pv) { v2 = v1; v1 = v; pv = p; }
                else { v2 = fmaxf(v2, v); }
            }
#pragma unroll
            for (int msk = 1; msk < 16; msk <<= 1) {          // 16 lanes share a row
                unsigned long long opv = __shfl_xor(pv, msk);
                float ov1 = __shfl_xor(v1, msk);
                float ov2 = __shfl_xor(v2, msk);
                if (opv > pv) { v2 = fmaxf(v1, ov2); v1 = ov1; pv = opv; }
                else          { v2 = fmaxf(v2, ov1); }
            }
            if (lrow == 0) {
                int row_blk = wrow * 64 + fi * 16 + quad * 4 + r;
                uint4 e;
                e.x = (unsigned int)(pv & 0xFFFFFFFFull);
                e.y = (unsigned int)(pv >> 32);
                e.z = __float_as_uint(v2);
                e.w = __float_as_uint(v1);
                sRed[row_blk][wcol] = e;
            }
        }
    }
    __syncthreads();

    if (tid < BM) {   // final 4-way merge per row, store + flag
        unsigned long long pv = 0; float v1 = -3.4e38f, v2 = -3.4e38f;
#pragma unroll
        for (int wc = 0; wc < 4; ++wc) {
            uint4 e = sRed[tid][wc];
            unsigned long long opv = ((unsigned long long)e.y << 32) | e.x;
            float ov1 = __uint_as_float(e.w), ov2 = __uint_as_float(e.z);
            if (opv > pv) { v2 = fmaxf(v1, ov2); v1 = ov1; pv = opv; }
            else          { v2 = fmaxf(v2, ov1); }
        }
        packed[(size_t)(m0 + tid) * GRP + bx] = pv;           // block-exclusive
        if (v1 - v2 <= MARGIN) {
            unsigned int slot = atomicAdd(flagcnt, 1u);
            flaglist[slot] = ((unsigned int)(m0 + tid) << 1) | (unsigned int)bx;
        }
    }
}

// ---------------- exact fp32 recheck of flagged (row, group) --------------------
__global__ __launch_bounds__(320)
void recheck(const float* __restrict__ A, const float* __restrict__ W,
             const float* __restrict__ bias,
             const unsigned int* __restrict__ flagcnt,
             const unsigned int* __restrict__ flaglist,
             unsigned long long* __restrict__ packed)
{
    __shared__ float  sAr[K_TOT];      // 19456 B
    __shared__ float4 sPart[320];
    __shared__ float  sVals[NV];
    const int tid = threadIdx.x;
    const unsigned int cnt = *flagcnt;
    const int kseg = tid / 80, c4 = tid % 80;   // 4 k-segments x 80 col-quads
    for (unsigned int i = blockIdx.x; i < cnt; i += gridDim.x) {
        unsigned int item = flaglist[i];
        int row = (int)(item >> 1), g = (int)(item & 1);
        __syncthreads();
        for (int l = tid; l < K_TOT / 4; l += 320)
            *(float4*)&sAr[l * 4] = *(const float4*)(A + (size_t)row * K_TOT + l * 4);
        __syncthreads();
        float4 acc = {0.f, 0.f, 0.f, 0.f};
        const float* wp = W + (size_t)(kseg * 1216) * N_TOT + g * NV + c4 * 4;
        const float* ap = sAr + kseg * 1216;
        for (int k = 0; k < 1216; ++k) {
            float a = ap[k];
            float4 wv = *(const float4*)(wp + (size_t)k * N_TOT);
            acc.x = fmaf(a, wv.x, acc.x);
            acc.y = fmaf(a, wv.y, acc.y);
            acc.z = fmaf(a, wv.z, acc.z);
            acc.w = fmaf(a, wv.w, acc.w);
        }
        sPart[tid] = acc;
        __syncthreads();
        if (tid < 80) {
            float4 s = {0.f, 0.f, 0.f, 0.f};
#pragma unroll
            for (int ks = 0; ks < 4; ++ks) {          // fixed order: deterministic
                float4 p = sPart[ks * 80 + tid];
                s.x += p.x; s.y += p.y; s.z += p.z; s.w += p.w;
            }
            float4 bb = *(const float4*)(bias + g * NV + tid * 4);
            sVals[tid * 4 + 0] = s.x + bb.x;
            sVals[tid * 4 + 1] = s.y + bb.y;
            sVals[tid * 4 + 2] = s.z + bb.z;
            sVals[tid * 4 + 3] = s.w + bb.w;
        }
        __syncthreads();
        if (tid == 0) {
            float best = sVals[0]; int bi = 0;
            for (int c = 1; c < NV; ++c)
                if (sVals[c] > best) { best = sVals[c]; bi = c; }   // first max wins
            packed[(size_t)row * GRP + g] =
                ((unsigned long long)mono_u32(best) << 32) | (unsigned int)(NV - 1 - bi);
        }
    }
}

// ---------------- gather + histogram, perplexity --------------------------------
__global__ __launch_bounds__(256)
void gather_hist(const unsigned long long* __restrict__ packed,
                 const float* __restrict__ cv,
                 float* __restrict__ out, int* __restrict__ counts)
{
    const int m = blockIdx.x;
    const int t = threadIdx.x;
    const int g = t >> 7;
    const unsigned long long p = packed[(size_t)m * GRP + g];
    const int idx = (NV - 1) - (int)(p & 0xFFFFFFFFull);
    const int c = t & 127;
    out[(size_t)m * (GRP * CVD) + t] = cv[((size_t)g * NV + idx) * CVD + c];
    if (c == 0) atomicAdd(&counts[g * NV + idx], 1);
}

__global__ void perplexity_k(const int* __restrict__ counts, float* __restrict__ outp)
{
    __shared__ float sred[GRP * NV];
    const int t = threadIdx.x;        // 640
    const float marg = (float)counts[t] * (1.0f / (float)M_TOT);
    sred[t] = marg * logf(marg + 1e-7f);
    __syncthreads();
    if (t < GRP) {
        float s = 0.f;
        for (int i = 0; i < NV; ++i) s += sred[t * NV + i];
        sred[t] = expf(-s);
    }
    __syncthreads();
    if (t == 0) outp[0] = sred[0] + sred[1];
}

extern "C" void kernel_launch(void* const* d_in, const int* in_sizes, int n_in,
                              void* d_out, int out_size, void* d_ws, size_t ws_size,
                              hipStream_t stream)
{
    const float* A    = (const float*)d_in[0];   // (16,1024,4864) f32
    const float* Wm   = (const float*)d_in[1];   // (4864,640) f32
    const float* bias = (const float*)d_in[2];   // (640,) f32
    const float* cv   = (const float*)d_in[3];   // (1,640,128) f32

    float* out = (float*)d_out;                       // (16,1024,256)
    float* ppl = out + (size_t)M_TOT * (GRP * CVD);   // +1 scalar

    char* ws = (char*)d_ws;
    unsigned int*       flagcnt  = (unsigned int*)(ws + WS_FLAGCNT);
    int*                counts   = (int*)(ws + WS_COUNTS);
    unsigned int*       flaglist = (unsigned int*)(ws + WS_FLAGLIST);
    unsigned long long* packed   = (unsigned long long*)(ws + WS_PACKED);
    unsigned short*     wt       = (unsigned short*)(ws + WS_WT);

    hipMemsetAsync(d_ws, 0, 4096, stream);            // flagcnt + counts
    convert_wt<<<dim3(76, 10), 256, 0, stream>>>(Wm, wt);
    gemm_mfma<<<dim3(2, 128), 512, 0, stream>>>(A, wt, bias, packed, flagcnt, flaglist);
    recheck<<<256, 320, 0, stream>>>(A, Wm, bias, flagcnt, flaglist, packed);
    gather_hist<<<M_TOT, 256, 0, stream>>>(packed, cv, out, counts);
    perplexity_k<<<1, GRP * NV, 0, stream>>>(counts, ppl);
}